// Round 10
// baseline (483.381 us; speedup 1.0000x reference)
//
#include <hip/hip_runtime.h>
#include <cmath>

typedef unsigned int uint32;
typedef __bf16 bf16;
typedef __bf16 bf16x8 __attribute__((ext_vector_type(8)));
typedef float f32x4 __attribute__((ext_vector_type(4)));

#define LVLS 10
#define TSIZE 65536
#define TMASK 65535u
#define PRIME2 2654435761u
#define PRIME3 805459861u

// ---- ws layout (bytes) ----
//   [0,      18432): W1t/W2t/W3t bf16 images (9216 elems; W1 input perm k'=l*4+d)
//   [18432,  18472): dq[10] f32  (scale/127 per level)
//   [18496,  18536): scales[10] u32 (absmax bits, atomicMax target; memset 0)
//   [18560,  2640000): uint8 table [10][65536][4], biased +128 (64B-aligned)
//   [2640000, 2659712): DENSE l0 [17][17][17] u32 (MODE 2 path)
//   [2659712, 2831212): DENSE l1 [35][35][35] u32 (MODE 2 path)
//   [2831232, 2870536): PAIR  l0 [17][17][17] u32x2 (z,z+1) (MODE 3)
//   [2870592, 3213592): PAIR  l1 [35][35][35] u32x2 (MODE 3)
//   [3213632, 4901132): DENSE l2 [75][75][75] u32 (MODE 3)
//   All dense/pair values built with the IDENTICAL quant4 as the hashed table
//   -> encode output is bit-identical across modes.
#define WOFF_W1 0
#define WOFF_W2 4096
#define WOFF_W3 8192
#define W_ELEMS 9216
#define DQ_OFF 18432
#define SC_OFF 18496
#define TAB_OFF_B 18560
#define TAB_ELEMS_F (LVLS * TSIZE * 4)   // f32 source elems
#define WS_NEEDED ((size_t)TAB_OFF_B + (size_t)TAB_ELEMS_F)   // 2,640,000
#define D0 17
#define D1 35
#define D2 75
#define DENSE0_OFF 2640000
#define DENSE0_N (D0 * D0 * D0)          // 4913
#define DENSE1_OFF 2659712
#define DENSE1_N (D1 * D1 * D1)          // 42875
#define WS_FULL ((size_t)DENSE1_OFF + (size_t)DENSE1_N * 4)   // 2,831,212
#define PAIR0_OFF 2831232
#define PAIR1_OFF 2870592
#define DENSE2_OFF 3213632
#define DENSE2_N (D2 * D2 * D2)          // 421875
#define WS_FULL3 ((size_t)DENSE2_OFF + (size_t)DENSE2_N * 4)  // 4,901,132

struct KParams { float resf[LVLS]; };

// ---------------- prep 1: per-level absmax ----------------
__global__ void scale_kernel(const float* __restrict__ tables, unsigned* __restrict__ scales) {
  int tid = blockIdx.x * 256 + threadIdx.x;
  int i4 = tid * 4;
  if (i4 >= TAB_ELEMS_F) return;
  float4 v = *(const float4*)(tables + i4);
  float m = fmaxf(fmaxf(fabsf(v.x), fabsf(v.y)), fmaxf(fabsf(v.z), fabsf(v.w)));
#pragma unroll
  for (int off = 32; off; off >>= 1) m = fmaxf(m, __shfl_xor(m, off, 64));
  if ((threadIdx.x & 63) == 0) {
    int l = i4 >> 18;  // 65536*4 = 2^18 elems per level; waves never straddle
    atomicMax(scales + l, __float_as_uint(m));
  }
}

// ---------------- prep 2: weight transpose + int8 quantize (biased +128) ----------------
// quantize one f32x4 entry -> packed biased-u8 (EXACT same ops everywhere so
// dense/pair remaps are bit-identical to the hashed table).
__device__ __forceinline__ unsigned quant4(float4 v, float s) {
  float r = (s > 0.f) ? 127.f / s : 0.f;
  int q0 = (int)rintf(fminf(fmaxf(v.x * r, -127.f), 127.f)) + 128;
  int q1 = (int)rintf(fminf(fmaxf(v.y * r, -127.f), 127.f)) + 128;
  int q2 = (int)rintf(fminf(fmaxf(v.z * r, -127.f), 127.f)) + 128;
  int q3 = (int)rintf(fminf(fmaxf(v.w * r, -127.f), 127.f)) + 128;
  return (q0 & 0xff) | ((q1 & 0xff) << 8) | ((q2 & 0xff) << 16) | ((q3 & 0xff) << 24);
}

__device__ __forceinline__ uint32 hash3(uint32 x, uint32 y, uint32 z) {
  return (x ^ (y * PRIME2) ^ (z * PRIME3)) & TMASK;
}

__global__ void quant_kernel(const float* __restrict__ W1, const float* __restrict__ W2,
                             const float* __restrict__ W3, const float* __restrict__ tables,
                             char* __restrict__ ws8, int do_tab) {
  int tid = blockIdx.x * 256 + threadIdx.x;
  bf16* wsb = (bf16*)ws8;
  if (tid < W_ELEMS) {
    float v;
    if (tid < 4096) {
      // W1 image with PERMUTED input index: k' = l*4 + d  <->  k = d*10 + l.
      int n = tid >> 6, kp_ = tid & 63;
      if (kp_ < 40) {
        int l = kp_ >> 2, d = kp_ & 3;
        v = W1[(d * 10 + l) * 64 + n];
      } else v = 0.f;
    } else if (tid < 8192) {
      int t2 = tid - 4096; int n = t2 >> 6, k = t2 & 63;
      v = W2[k * 64 + n];
    } else {
      int t3 = tid - 8192; int n = t3 >> 6, k = t3 & 63;
      v = (n < 13) ? W3[k * 13 + n] : 0.f;
    }
    wsb[tid] = (bf16)v;
  }
  const unsigned* scales = (const unsigned*)(ws8 + SC_OFF);
  if (tid < LVLS) {
    float s = __uint_as_float(scales[tid]);
    ((float*)(ws8 + DQ_OFF))[tid] = s * (1.0f / 127.0f);
  }
  if (do_tab >= 1) {
    int i4 = tid * 4;
    if (i4 < TAB_ELEMS_F) {
      float4 v = *(const float4*)(tables + i4);
      int l = i4 >> 18;
      float s = __uint_as_float(scales[l]);
      *(unsigned*)(ws8 + TAB_OFF_B + i4) = quant4(v, s);
    }
  }
  if (do_tab == 2) {
    // MODE-2 dense remaps (u32) for the coarse levels.
    const float4* t4 = (const float4*)tables;
    if (tid < DENSE0_N) {
      int z = tid % D0, y = (tid / D0) % D0, xx = tid / (D0 * D0);
      float s = __uint_as_float(scales[0]);
      ((unsigned*)(ws8 + DENSE0_OFF))[tid] = quant4(t4[0 * TSIZE + hash3(xx, y, z)], s);
    }
    if (tid < DENSE1_N) {
      int z = tid % D1, y = (tid / D1) % D1, xx = tid / (D1 * D1);
      float s = __uint_as_float(scales[1]);
      ((unsigned*)(ws8 + DENSE1_OFF))[tid] = quant4(t4[1 * TSIZE + hash3(xx, y, z)], s);
    }
  }
  if (do_tab >= 3) {
    // MODE-3 pair tables (l0,l1: entry = (val[z], val[z+1])) + dense l2.
    const float4* t4 = (const float4*)tables;
    if (tid < DENSE0_N) {
      int z = tid % D0, y = (tid / D0) % D0, xx = tid / (D0 * D0);
      float s = __uint_as_float(scales[0]);
      uint2 p;
      p.x = quant4(t4[0 * TSIZE + hash3(xx, y, z)], s);
      p.y = quant4(t4[0 * TSIZE + hash3(xx, y, z + 1)], s);
      ((uint2*)(ws8 + PAIR0_OFF))[tid] = p;
    }
    if (tid < DENSE1_N) {
      int z = tid % D1, y = (tid / D1) % D1, xx = tid / (D1 * D1);
      float s = __uint_as_float(scales[1]);
      uint2 p;
      p.x = quant4(t4[1 * TSIZE + hash3(xx, y, z)], s);
      p.y = quant4(t4[1 * TSIZE + hash3(xx, y, z + 1)], s);
      ((uint2*)(ws8 + PAIR1_OFF))[tid] = p;
    }
    if (tid < DENSE2_N) {
      int z = tid % D2, y = (tid / D2) % D2, xx = tid / (D2 * D2);
      float s = __uint_as_float(scales[2]);
      ((unsigned*)(ws8 + DENSE2_OFF))[tid] = quant4(t4[2 * TSIZE + hash3(xx, y, z)], s);
    }
  }
}

// ---------------- device helpers ----------------
__device__ __forceinline__ float selu_f(float v) {
  float neg = 1.6732632423543772f * (__expf(v) - 1.0f);
  return 1.0507009873554805f * (v > 0.f ? v : neg);
}

// Hbuf: 256 rows x 128 B (stride 64 bf16), XOR-swizzled at 16B granularity so
// 16-lanes-read-16-rows-same-col (GEMM A-operand pattern) is conflict-free.
__device__ __forceinline__ bf16* hswz(bf16* Hb, int row, int cb) {
  return (bf16*)((char*)Hb + (row << 7) + (cb ^ ((row & 7) << 4)));
}

// One hidden-layer GEMM stage, split into two 32-col halves (lower peak reg
// pressure). A-fragments hoisted into registers BEFORE any H-write (in-place).
__device__ __forceinline__ void gemm_stage(bf16* __restrict__ Hb, int w, int lr, int quad,
                                           const bf16* __restrict__ Bbase,
                                           const float* __restrict__ bvec) {
  bf16x8 Af[2][4];
#pragma unroll
  for (int ks = 0; ks < 2; ++ks)
#pragma unroll
    for (int ms = 0; ms < 4; ++ms)
      Af[ks][ms] = *(const bf16x8*)hswz(Hb, w * 64 + ms * 16 + lr, quad * 16 + ks * 64);
#pragma unroll
  for (int h = 0; h < 2; ++h) {
    f32x4 acc[4][2];
#pragma unroll
    for (int nt2 = 0; nt2 < 2; ++nt2) {
      float b = bvec[(h * 2 + nt2) * 16 + lr];
#pragma unroll
      for (int ms = 0; ms < 4; ++ms) {
        f32x4 a = {b, b, b, b};
        acc[ms][nt2] = a;
      }
    }
#pragma unroll
    for (int ks = 0; ks < 2; ++ks) {
      bf16x8 B0 = *(const bf16x8*)(Bbase + (h * 2 + 0) * 1024 + ks * 32);
      bf16x8 B1 = *(const bf16x8*)(Bbase + (h * 2 + 1) * 1024 + ks * 32);
#pragma unroll
      for (int ms = 0; ms < 4; ++ms) {
        acc[ms][0] = __builtin_amdgcn_mfma_f32_16x16x32_bf16(Af[ks][ms], B0, acc[ms][0], 0, 0, 0);
        acc[ms][1] = __builtin_amdgcn_mfma_f32_16x16x32_bf16(Af[ks][ms], B1, acc[ms][1], 0, 0, 0);
      }
    }
#pragma unroll
    for (int ms = 0; ms < 4; ++ms)
#pragma unroll
      for (int nt2 = 0; nt2 < 2; ++nt2)
#pragma unroll
        for (int r = 0; r < 4; ++r) {
          int row = w * 64 + quad * 4 + ms * 16 + r;
          *hswz(Hb, row, ((h * 2 + nt2) * 16 + lr) * 2) = (bf16)selu_f(acc[ms][nt2][r]);
        }
  }
}

// level offset (l<<16) folded into idx so gathers are a single uniform base.
#define CALC_IDX(L, IDX, F0, F1, F2)                                   \
  do {                                                                 \
    const float rs_ = kp.resf[(L)];                                    \
    float xs_ = px * rs_, ys_ = py * rs_, zs_ = pz * rs_;              \
    float bx_ = floorf(xs_), by_ = floorf(ys_), bz_ = floorf(zs_);     \
    (F0) = xs_ - bx_; (F1) = ys_ - by_; (F2) = zs_ - bz_;              \
    uint32 cx_ = (uint32)bx_, cy_ = (uint32)by_, cz_ = (uint32)bz_;    \
    uint32 hy0_ = cy_ * PRIME2, hy1_ = hy0_ + PRIME2;                  \
    uint32 hz0_ = cz_ * PRIME3, hz1_ = hz0_ + PRIME3;                  \
    uint32 cx1_ = cx_ + 1u;                                            \
    uint32 bse_ = (uint32)(L) << 16;                                   \
    (IDX)[0] = ((cx_ ^ hy0_ ^ hz0_) & TMASK) | bse_;                   \
    (IDX)[1] = ((cx_ ^ hy0_ ^ hz1_) & TMASK) | bse_;                   \
    (IDX)[2] = ((cx_ ^ hy1_ ^ hz0_) & TMASK) | bse_;                   \
    (IDX)[3] = ((cx_ ^ hy1_ ^ hz1_) & TMASK) | bse_;                   \
    (IDX)[4] = ((cx1_ ^ hy0_ ^ hz0_) & TMASK) | bse_;                  \
    (IDX)[5] = ((cx1_ ^ hy0_ ^ hz1_) & TMASK) | bse_;                  \
    (IDX)[6] = ((cx1_ ^ hy1_ ^ hz0_) & TMASK) | bse_;                  \
    (IDX)[7] = ((cx1_ ^ hy1_ ^ hz1_) & TMASK) | bse_;                  \
  } while (0)

// dense remap index calc: z-fastest [x][y][z], corner order matches CALC_IDX
// ((dx,dy,dz) = 000,001,010,011,100,101,110,111).
#define CALC_IDX_DENSE(L, DD, IDX, F0, F1, F2)                         \
  do {                                                                 \
    const float rs_ = kp.resf[(L)];                                    \
    float xs_ = px * rs_, ys_ = py * rs_, zs_ = pz * rs_;              \
    float bx_ = floorf(xs_), by_ = floorf(ys_), bz_ = floorf(zs_);     \
    (F0) = xs_ - bx_; (F1) = ys_ - by_; (F2) = zs_ - bz_;              \
    uint32 cx_ = (uint32)bx_, cy_ = (uint32)by_, cz_ = (uint32)bz_;    \
    uint32 b_ = (cx_ * (uint32)(DD) + cy_) * (uint32)(DD) + cz_;       \
    (IDX)[0] = b_;                                                     \
    (IDX)[1] = b_ + 1u;                                                \
    (IDX)[2] = b_ + (uint32)(DD);                                      \
    (IDX)[3] = b_ + (uint32)(DD) + 1u;                                 \
    (IDX)[4] = b_ + (uint32)((DD) * (DD));                             \
    (IDX)[5] = b_ + (uint32)((DD) * (DD)) + 1u;                        \
    (IDX)[6] = b_ + (uint32)((DD) * (DD) + (DD));                      \
    (IDX)[7] = b_ + (uint32)((DD) * (DD) + (DD)) + 1u;                 \
  } while (0)

// ---------------- fused encode + MLP ----------------
// 256 threads (4 waves), 256 points per block. MODE 1 = verified r3 artifact;
// MODE 2 = r9 (dense l0/l1, PASSED, 281.5us); MODE 3 adds pair-packed l0/l1
// (4x8B loads instead of 8x4B -> half the address transactions) + dense l2.
// HISTORY (do not regress):
//  - r1/r2: feat[40] spills (FETCH 410/216MB). r3: clean, 289us, PASSED.
//  - r4/r5: split-point occupancy experiments: more TLP is NOT the lever.
//  - r6/r7: load-schedule reorders of the hashed path: FAILED correctness,
//    unexplained. Do NOT reorder the hashed-level loads.
//  - r8 = r3 restore: PASSED 289us. r9 = MODE 2: PASSED 281.5us (+2.6%) —
//    footprint-only gain small => encode is ADDRESS-TRANSACTION bound.
//  - NOW MODE 3: cut transaction count (80->72 loads/point, l2 line-sharing).
template <int MODE>
__global__ __launch_bounds__(256, 4)
void ngp_fused(const float* __restrict__ x, const float* __restrict__ cr,
               const float* __restrict__ tables, const char* __restrict__ ws8,
               const float* __restrict__ b1, const float* __restrict__ b2,
               const float* __restrict__ b3, float* __restrict__ out,
               int N, KParams kp) {
  __shared__ __align__(16) bf16 Hbuf[256 * 64];
  const int tid = threadIdx.x;
  const int n = blockIdx.x * 256 + tid;
  const int ncl = (n < N) ? n : 0;

  const float px = x[ncl * 3 + 0];
  const float py = x[ncl * 3 + 1];
  const float pz = x[ncl * 3 + 2];
  const float crv = cr[ncl];
  const float* dq = (const float*)(ws8 + DQ_OFF);

  // ---- encode: stream one level-pair (8 bf16 = 16 B) to LDS per group ----
#pragma unroll
  for (int g = 0; g < 5; ++g) {
    bf16x8 v;
#pragma unroll
    for (int h = 0; h < 2; ++h) {
      const int l = g * 2 + h;
      float fx, fy, fz;
      float a0 = 0.f, a1 = 0.f, a2 = 0.f, a3 = 0.f;
      if constexpr (MODE >= 1) {
        unsigned q[8];
        if (MODE == 3 && g == 0) {
          // pair-packed dense: 4 x 8B gathers (corners (z,z+1) per entry).
          const float rs_ = kp.resf[l];
          float xs_ = px * rs_, ys_ = py * rs_, zs_ = pz * rs_;
          float bx_ = floorf(xs_), by_ = floorf(ys_), bz_ = floorf(zs_);
          fx = xs_ - bx_; fy = ys_ - by_; fz = zs_ - bz_;
          uint32 cx_ = (uint32)bx_, cy_ = (uint32)by_, cz_ = (uint32)bz_;
          const uint32 DDc = h ? (uint32)D1 : (uint32)D0;
          uint32 b_ = (cx_ * DDc + cy_) * DDc + cz_;
          const uint2* pt = (const uint2*)(ws8 + (h ? PAIR1_OFF : PAIR0_OFF));
          uint2 P0 = pt[b_];
          uint2 P1 = pt[b_ + DDc];
          uint2 P2 = pt[b_ + DDc * DDc];
          uint2 P3 = pt[b_ + DDc * DDc + DDc];
          q[0] = P0.x; q[1] = P0.y; q[2] = P1.x; q[3] = P1.y;
          q[4] = P2.x; q[5] = P2.y; q[6] = P3.x; q[7] = P3.y;
        } else if (MODE == 2 && g == 0) {
          uint32 idx[8];
          const unsigned* tb;
          if (h == 0) {
            CALC_IDX_DENSE(0, D0, idx, fx, fy, fz);
            tb = (const unsigned*)(ws8 + DENSE0_OFF);
          } else {
            CALC_IDX_DENSE(1, D1, idx, fx, fy, fz);
            tb = (const unsigned*)(ws8 + DENSE1_OFF);
          }
#pragma unroll
          for (int c = 0; c < 8; ++c) q[c] = tb[idx[c]];
        } else if (MODE == 3 && g == 1 && h == 0) {
          uint32 idx[8];
          CALC_IDX_DENSE(2, D2, idx, fx, fy, fz);
          const unsigned* tb = (const unsigned*)(ws8 + DENSE2_OFF);
#pragma unroll
          for (int c = 0; c < 8; ++c) q[c] = tb[idx[c]];
        } else {
          uint32 idx[8];
          CALC_IDX(l, idx, fx, fy, fz);
          const unsigned* tb = (const unsigned*)(ws8 + TAB_OFF_B);
#pragma unroll
          for (int c = 0; c < 8; ++c) q[c] = tb[idx[c]];
        }
        float wx1 = fx, wx0 = 1.f - fx, wy1 = fy, wy0 = 1.f - fy, wz1 = fz, wz0 = 1.f - fz;
        float wxy00 = wx0 * wy0, wxy01 = wx0 * wy1, wxy10 = wx1 * wy0, wxy11 = wx1 * wy1;
        float w8[8] = {wxy00 * wz0, wxy00 * wz1, wxy01 * wz0, wxy01 * wz1,
                       wxy10 * wz0, wxy10 * wz1, wxy11 * wz0, wxy11 * wz1};
#pragma unroll
        for (int c = 0; c < 8; ++c) {
          // biased-ubyte unpack -> v_cvt_f32_ubyte{0..3}; the -128*sum(w) term
          // folds to -128 exactly (trilinear weights sum to 1).
          unsigned q_ = q[c];
          a0 = fmaf(w8[c], (float)(q_ & 0xffu), a0);
          a1 = fmaf(w8[c], (float)((q_ >> 8) & 0xffu), a1);
          a2 = fmaf(w8[c], (float)((q_ >> 16) & 0xffu), a2);
          a3 = fmaf(w8[c], (float)(q_ >> 24), a3);
        }
        // l==0: erf(rsqrt(1e-12)) == 1.0f exactly -> skip the transcendental.
        float s = (l == 0) ? dq[0]
                           : erff(rsqrtf(fmaxf(4.0f * (float)l * crv, 1e-12f))) * dq[l];
        v[h * 4 + 0] = (bf16)((a0 - 128.f) * s);
        v[h * 4 + 1] = (bf16)((a1 - 128.f) * s);
        v[h * 4 + 2] = (bf16)((a2 - 128.f) * s);
        v[h * 4 + 3] = (bf16)((a3 - 128.f) * s);
      } else {
        uint32 idx[8];
        CALC_IDX(l, idx, fx, fy, fz);
        const float4* tb4 = (const float4*)tables;  // idx already has l<<16 folded
        float f[8][4];
#pragma unroll
        for (int c = 0; c < 8; ++c) {
          float4 q = tb4[idx[c]];
          f[c][0] = q.x; f[c][1] = q.y; f[c][2] = q.z; f[c][3] = q.w;
        }
        float wx1 = fx, wx0 = 1.f - fx, wy1 = fy, wy0 = 1.f - fy, wz1 = fz, wz0 = 1.f - fz;
        float wxy00 = wx0 * wy0, wxy01 = wx0 * wy1, wxy10 = wx1 * wy0, wxy11 = wx1 * wy1;
        float w8[8] = {wxy00 * wz0, wxy00 * wz1, wxy01 * wz0, wxy01 * wz1,
                       wxy10 * wz0, wxy10 * wz1, wxy11 * wz0, wxy11 * wz1};
#pragma unroll
        for (int c = 0; c < 8; ++c) {
          a0 = fmaf(w8[c], f[c][0], a0);
          a1 = fmaf(w8[c], f[c][1], a1);
          a2 = fmaf(w8[c], f[c][2], a2);
          a3 = fmaf(w8[c], f[c][3], a3);
        }
        float s = (l == 0) ? 1.0f : erff(rsqrtf(fmaxf(4.0f * (float)l * crv, 1e-12f)));
        v[h * 4 + 0] = (bf16)(a0 * s);
        v[h * 4 + 1] = (bf16)(a1 * s);
        v[h * 4 + 2] = (bf16)(a2 * s);
        v[h * 4 + 3] = (bf16)(a3 * s);
      }
    }
    *(bf16x8*)hswz(Hbuf, tid, g * 16) = v;
  }
  {
    bf16x8 z;
#pragma unroll
    for (int j = 0; j < 8; ++j) z[j] = (bf16)0.f;
    *(bf16x8*)hswz(Hbuf, tid, 80) = z;
    *(bf16x8*)hswz(Hbuf, tid, 96) = z;
    *(bf16x8*)hswz(Hbuf, tid, 112) = z;
  }
  __syncthreads();

  const int w = tid >> 6;
  const int lane = tid & 63;
  const int lr = lane & 15;
  const int quad = lane >> 4;
  const bf16* wsb = (const bf16*)ws8;

  gemm_stage(Hbuf, w, lr, quad, wsb + WOFF_W1 + lr * 64 + quad * 8, b1);
  __syncthreads();
  gemm_stage(Hbuf, w, lr, quad, wsb + WOFF_W2 + lr * 64 + quad * 8, b2);
  __syncthreads();

  // ---- stage 3 (64 -> 13) + LDS-staged coalesced output ----
  {
    float b3v = (lr < 13) ? b3[lr] : 0.f;
    f32x4 acc3[4];
#pragma unroll
    for (int ms = 0; ms < 4; ++ms) {
      f32x4 a = {b3v, b3v, b3v, b3v};
      acc3[ms] = a;
    }
    const bf16* B3b = wsb + WOFF_W3 + lr * 64 + quad * 8;
    bf16x8 B3[2];
    B3[0] = *(const bf16x8*)(B3b);
    B3[1] = *(const bf16x8*)(B3b + 32);
#pragma unroll
    for (int ks = 0; ks < 2; ++ks) {
      bf16x8 Af[4];
#pragma unroll
      for (int ms = 0; ms < 4; ++ms)
        Af[ms] = *(const bf16x8*)hswz(Hbuf, w * 64 + ms * 16 + lr, quad * 16 + ks * 64);
#pragma unroll
      for (int ms = 0; ms < 4; ++ms)
        acc3[ms] = __builtin_amdgcn_mfma_f32_16x16x32_bf16(Af[ms], B3[ks], acc3[ms], 0, 0, 0);
    }
    __syncthreads();  // done reading Hbuf; reuse it as f32 output stage
    float* Obuf = (float*)Hbuf;  // 256*13*4 = 13312 B <= 32768 B
#pragma unroll
    for (int ms = 0; ms < 4; ++ms)
#pragma unroll
      for (int r = 0; r < 4; ++r)
        if (lr < 13)
          Obuf[(w * 64 + quad * 4 + ms * 16 + r) * 13 + lr] = acc3[ms][r];
    __syncthreads();

    const int base = blockIdx.x * 256;
    int nrows = N - base;
    if (nrows >= 256) {
      // 13312 B per block, 64B-aligned, fully coalesced float4 stores.
      float4* og4 = (float4*)(out + (size_t)base * 13);
      const float4* Ob4 = (const float4*)Obuf;
#pragma unroll
      for (int i = 0; i < 4; ++i) {
        int j = tid + i * 256;
        if (j < 832) og4[j] = Ob4[j];
      }
    } else {
      const int nfl = nrows * 13;
      float* og = out + (size_t)base * 13;
      for (int j = tid; j < nfl; j += 256) og[j] = Obuf[j];
    }
  }
}

// ---------------- host ----------------
extern "C" void kernel_launch(void* const* d_in, const int* in_sizes, int n_in,
                              void* d_out, int out_size, void* d_ws, size_t ws_size,
                              hipStream_t stream) {
  const float* x      = (const float*)d_in[0];
  const float* cr     = (const float*)d_in[1];
  const float* tables = (const float*)d_in[2];
  const float* W1     = (const float*)d_in[3];
  const float* b1     = (const float*)d_in[4];
  const float* W2     = (const float*)d_in[5];
  const float* b2     = (const float*)d_in[6];
  const float* W3     = (const float*)d_in[7];
  const float* b3     = (const float*)d_in[8];
  float* out = (float*)d_out;
  const int N = in_sizes[1];

  // RES with the exact double arithmetic Python uses (bit-identical hashing).
  KParams kp;
  double B = exp((log(16.0 * pow(2.0, 10.0)) - log(16.0)) / 9.0);
  for (int l = 0; l < LVLS; ++l) kp.resf[l] = (float)floor(16.0 * pow(B, (double)l));

  char* ws8 = (char*)d_ws;
  const int mode = (ws_size >= WS_FULL3) ? 3
                 : (ws_size >= WS_FULL)  ? 2
                 : (ws_size >= WS_NEEDED) ? 1 : 0;

  const int qblocks = (TAB_ELEMS_F / 4 + 255) / 256;  // 2560: covers all builds
  if (mode >= 1) {
    hipMemsetAsync(ws8 + SC_OFF, 0, 64, stream);
    scale_kernel<<<qblocks, 256, 0, stream>>>(tables, (unsigned*)(ws8 + SC_OFF));
    quant_kernel<<<qblocks, 256, 0, stream>>>(W1, W2, W3, tables, ws8, mode);
  } else {
    quant_kernel<<<(W_ELEMS + 255) / 256, 256, 0, stream>>>(W1, W2, W3, tables, ws8, 0);
  }

  int blocks = (N + 255) / 256;
  if (mode == 3)
    ngp_fused<3><<<blocks, 256, 0, stream>>>(x, cr, tables, ws8, b1, b2, b3, out, N, kp);
  else if (mode == 2)
    ngp_fused<2><<<blocks, 256, 0, stream>>>(x, cr, tables, ws8, b1, b2, b3, out, N, kp);
  else if (mode == 1)
    ngp_fused<1><<<blocks, 256, 0, stream>>>(x, cr, tables, ws8, b1, b2, b3, out, N, kp);
  else
    ngp_fused<0><<<blocks, 256, 0, stream>>>(x, cr, tables, ws8, b1, b2, b3, out, N, kp);
}

// Round 11
// 469.988 us; speedup vs baseline: 1.0285x; 1.0285x over previous
//
#include <hip/hip_runtime.h>
#include <cmath>

typedef unsigned int uint32;
typedef __bf16 bf16;
typedef __bf16 bf16x8 __attribute__((ext_vector_type(8)));
typedef float f32x4 __attribute__((ext_vector_type(4)));

#define LVLS 10
#define TSIZE 65536
#define TMASK 65535u
#define PRIME2 2654435761u
#define PRIME3 805459861u

// ---- ws layout (bytes) ----
//   [0,      18432): W1t/W2t/W3t bf16 images (9216 elems; W1 input perm k'=l*4+d)
//   [18432,  18472): dq[10] f32  (scale/127 per level)
//   [18496,  18536): scales[10] u32 (absmax bits, atomicMax target; memset 0)
//   [18560,  2640000): uint8 table [10][65536][4], biased +128 (64B-aligned)
//   [2640000, 2659712): DENSE l0 [17][17][17] u32 (MODE 2 path)
//   [2659712, 2831212): DENSE l1 [35][35][35] u32 (MODE 2 path)
//   [2831232, 2870536): PAIR  l0 [17][17][17] u32x2 (z,z+1) (MODE 3)
//   [2870592, 3213592): PAIR  l1 [35][35][35] u32x2 (MODE 3)
//   NO dense l2: r10 proved it blows the 4MiB per-XCD L2 (FETCH 59->200MB).
//   All dense/pair values built with the IDENTICAL quant4 as the hashed table
//   -> encode output is bit-identical across modes.
#define WOFF_W1 0
#define WOFF_W2 4096
#define WOFF_W3 8192
#define W_ELEMS 9216
#define DQ_OFF 18432
#define SC_OFF 18496
#define TAB_OFF_B 18560
#define TAB_ELEMS_F (LVLS * TSIZE * 4)   // f32 source elems
#define WS_NEEDED ((size_t)TAB_OFF_B + (size_t)TAB_ELEMS_F)   // 2,640,000
#define D0 17
#define D1 35
#define DENSE0_OFF 2640000
#define DENSE0_N (D0 * D0 * D0)          // 4913
#define DENSE1_OFF 2659712
#define DENSE1_N (D1 * D1 * D1)          // 42875
#define WS_FULL ((size_t)DENSE1_OFF + (size_t)DENSE1_N * 4)   // 2,831,212
#define PAIR0_OFF 2831232
#define PAIR1_OFF 2870592
#define WS_FULL3 ((size_t)PAIR1_OFF + (size_t)DENSE1_N * 8)   // 3,213,592

struct KParams { float resf[LVLS]; };

// ---------------- prep 1: per-level absmax ----------------
__global__ void scale_kernel(const float* __restrict__ tables, unsigned* __restrict__ scales) {
  int tid = blockIdx.x * 256 + threadIdx.x;
  int i4 = tid * 4;
  if (i4 >= TAB_ELEMS_F) return;
  float4 v = *(const float4*)(tables + i4);
  float m = fmaxf(fmaxf(fabsf(v.x), fabsf(v.y)), fmaxf(fabsf(v.z), fabsf(v.w)));
#pragma unroll
  for (int off = 32; off; off >>= 1) m = fmaxf(m, __shfl_xor(m, off, 64));
  if ((threadIdx.x & 63) == 0) {
    int l = i4 >> 18;  // 65536*4 = 2^18 elems per level; waves never straddle
    atomicMax(scales + l, __float_as_uint(m));
  }
}

// ---------------- prep 2: weight transpose + int8 quantize (biased +128) ----------------
// quantize one f32x4 entry -> packed biased-u8 (EXACT same ops everywhere so
// dense/pair remaps are bit-identical to the hashed table).
__device__ __forceinline__ unsigned quant4(float4 v, float s) {
  float r = (s > 0.f) ? 127.f / s : 0.f;
  int q0 = (int)rintf(fminf(fmaxf(v.x * r, -127.f), 127.f)) + 128;
  int q1 = (int)rintf(fminf(fmaxf(v.y * r, -127.f), 127.f)) + 128;
  int q2 = (int)rintf(fminf(fmaxf(v.z * r, -127.f), 127.f)) + 128;
  int q3 = (int)rintf(fminf(fmaxf(v.w * r, -127.f), 127.f)) + 128;
  return (q0 & 0xff) | ((q1 & 0xff) << 8) | ((q2 & 0xff) << 16) | ((q3 & 0xff) << 24);
}

__device__ __forceinline__ uint32 hash3(uint32 x, uint32 y, uint32 z) {
  return (x ^ (y * PRIME2) ^ (z * PRIME3)) & TMASK;
}

__global__ void quant_kernel(const float* __restrict__ W1, const float* __restrict__ W2,
                             const float* __restrict__ W3, const float* __restrict__ tables,
                             char* __restrict__ ws8, int do_tab) {
  int tid = blockIdx.x * 256 + threadIdx.x;
  bf16* wsb = (bf16*)ws8;
  if (tid < W_ELEMS) {
    float v;
    if (tid < 4096) {
      // W1 image with PERMUTED input index: k' = l*4 + d  <->  k = d*10 + l.
      int n = tid >> 6, kp_ = tid & 63;
      if (kp_ < 40) {
        int l = kp_ >> 2, d = kp_ & 3;
        v = W1[(d * 10 + l) * 64 + n];
      } else v = 0.f;
    } else if (tid < 8192) {
      int t2 = tid - 4096; int n = t2 >> 6, k = t2 & 63;
      v = W2[k * 64 + n];
    } else {
      int t3 = tid - 8192; int n = t3 >> 6, k = t3 & 63;
      v = (n < 13) ? W3[k * 13 + n] : 0.f;
    }
    wsb[tid] = (bf16)v;
  }
  const unsigned* scales = (const unsigned*)(ws8 + SC_OFF);
  if (tid < LVLS) {
    float s = __uint_as_float(scales[tid]);
    ((float*)(ws8 + DQ_OFF))[tid] = s * (1.0f / 127.0f);
  }
  if (do_tab >= 1) {
    int i4 = tid * 4;
    if (i4 < TAB_ELEMS_F) {
      float4 v = *(const float4*)(tables + i4);
      int l = i4 >> 18;
      float s = __uint_as_float(scales[l]);
      *(unsigned*)(ws8 + TAB_OFF_B + i4) = quant4(v, s);
    }
  }
  if (do_tab == 2) {
    // MODE-2 dense remaps (u32) for the coarse levels.
    const float4* t4 = (const float4*)tables;
    if (tid < DENSE0_N) {
      int z = tid % D0, y = (tid / D0) % D0, xx = tid / (D0 * D0);
      float s = __uint_as_float(scales[0]);
      ((unsigned*)(ws8 + DENSE0_OFF))[tid] = quant4(t4[0 * TSIZE + hash3(xx, y, z)], s);
    }
    if (tid < DENSE1_N) {
      int z = tid % D1, y = (tid / D1) % D1, xx = tid / (D1 * D1);
      float s = __uint_as_float(scales[1]);
      ((unsigned*)(ws8 + DENSE1_OFF))[tid] = quant4(t4[1 * TSIZE + hash3(xx, y, z)], s);
    }
  }
  if (do_tab >= 3) {
    // MODE-3 pair tables (l0,l1: entry = (val[z], val[z+1])). NO dense l2.
    const float4* t4 = (const float4*)tables;
    if (tid < DENSE0_N) {
      int z = tid % D0, y = (tid / D0) % D0, xx = tid / (D0 * D0);
      float s = __uint_as_float(scales[0]);
      uint2 p;
      p.x = quant4(t4[0 * TSIZE + hash3(xx, y, z)], s);
      p.y = quant4(t4[0 * TSIZE + hash3(xx, y, z + 1)], s);
      ((uint2*)(ws8 + PAIR0_OFF))[tid] = p;
    }
    if (tid < DENSE1_N) {
      int z = tid % D1, y = (tid / D1) % D1, xx = tid / (D1 * D1);
      float s = __uint_as_float(scales[1]);
      uint2 p;
      p.x = quant4(t4[1 * TSIZE + hash3(xx, y, z)], s);
      p.y = quant4(t4[1 * TSIZE + hash3(xx, y, z + 1)], s);
      ((uint2*)(ws8 + PAIR1_OFF))[tid] = p;
    }
  }
}

// ---------------- device helpers ----------------
__device__ __forceinline__ float selu_f(float v) {
  float neg = 1.6732632423543772f * (__expf(v) - 1.0f);
  return 1.0507009873554805f * (v > 0.f ? v : neg);
}

// Hbuf: 256 rows x 128 B (stride 64 bf16), XOR-swizzled at 16B granularity so
// 16-lanes-read-16-rows-same-col (GEMM A-operand pattern) is conflict-free.
__device__ __forceinline__ bf16* hswz(bf16* Hb, int row, int cb) {
  return (bf16*)((char*)Hb + (row << 7) + (cb ^ ((row & 7) << 4)));
}

// One hidden-layer GEMM stage, split into two 32-col halves (lower peak reg
// pressure). A-fragments hoisted into registers BEFORE any H-write (in-place).
__device__ __forceinline__ void gemm_stage(bf16* __restrict__ Hb, int w, int lr, int quad,
                                           const bf16* __restrict__ Bbase,
                                           const float* __restrict__ bvec) {
  bf16x8 Af[2][4];
#pragma unroll
  for (int ks = 0; ks < 2; ++ks)
#pragma unroll
    for (int ms = 0; ms < 4; ++ms)
      Af[ks][ms] = *(const bf16x8*)hswz(Hb, w * 64 + ms * 16 + lr, quad * 16 + ks * 64);
#pragma unroll
  for (int h = 0; h < 2; ++h) {
    f32x4 acc[4][2];
#pragma unroll
    for (int nt2 = 0; nt2 < 2; ++nt2) {
      float b = bvec[(h * 2 + nt2) * 16 + lr];
#pragma unroll
      for (int ms = 0; ms < 4; ++ms) {
        f32x4 a = {b, b, b, b};
        acc[ms][nt2] = a;
      }
    }
#pragma unroll
    for (int ks = 0; ks < 2; ++ks) {
      bf16x8 B0 = *(const bf16x8*)(Bbase + (h * 2 + 0) * 1024 + ks * 32);
      bf16x8 B1 = *(const bf16x8*)(Bbase + (h * 2 + 1) * 1024 + ks * 32);
#pragma unroll
      for (int ms = 0; ms < 4; ++ms) {
        acc[ms][0] = __builtin_amdgcn_mfma_f32_16x16x32_bf16(Af[ks][ms], B0, acc[ms][0], 0, 0, 0);
        acc[ms][1] = __builtin_amdgcn_mfma_f32_16x16x32_bf16(Af[ks][ms], B1, acc[ms][1], 0, 0, 0);
      }
    }
#pragma unroll
    for (int ms = 0; ms < 4; ++ms)
#pragma unroll
      for (int nt2 = 0; nt2 < 2; ++nt2)
#pragma unroll
        for (int r = 0; r < 4; ++r) {
          int row = w * 64 + quad * 4 + ms * 16 + r;
          *hswz(Hb, row, ((h * 2 + nt2) * 16 + lr) * 2) = (bf16)selu_f(acc[ms][nt2][r]);
        }
  }
}

// level offset (l<<16) folded into idx so gathers are a single uniform base.
#define CALC_IDX(L, IDX, F0, F1, F2)                                   \
  do {                                                                 \
    const float rs_ = kp.resf[(L)];                                    \
    float xs_ = px * rs_, ys_ = py * rs_, zs_ = pz * rs_;              \
    float bx_ = floorf(xs_), by_ = floorf(ys_), bz_ = floorf(zs_);     \
    (F0) = xs_ - bx_; (F1) = ys_ - by_; (F2) = zs_ - bz_;              \
    uint32 cx_ = (uint32)bx_, cy_ = (uint32)by_, cz_ = (uint32)bz_;    \
    uint32 hy0_ = cy_ * PRIME2, hy1_ = hy0_ + PRIME2;                  \
    uint32 hz0_ = cz_ * PRIME3, hz1_ = hz0_ + PRIME3;                  \
    uint32 cx1_ = cx_ + 1u;                                            \
    uint32 bse_ = (uint32)(L) << 16;                                   \
    (IDX)[0] = ((cx_ ^ hy0_ ^ hz0_) & TMASK) | bse_;                   \
    (IDX)[1] = ((cx_ ^ hy0_ ^ hz1_) & TMASK) | bse_;                   \
    (IDX)[2] = ((cx_ ^ hy1_ ^ hz0_) & TMASK) | bse_;                   \
    (IDX)[3] = ((cx_ ^ hy1_ ^ hz1_) & TMASK) | bse_;                   \
    (IDX)[4] = ((cx1_ ^ hy0_ ^ hz0_) & TMASK) | bse_;                  \
    (IDX)[5] = ((cx1_ ^ hy0_ ^ hz1_) & TMASK) | bse_;                  \
    (IDX)[6] = ((cx1_ ^ hy1_ ^ hz0_) & TMASK) | bse_;                  \
    (IDX)[7] = ((cx1_ ^ hy1_ ^ hz1_) & TMASK) | bse_;                  \
  } while (0)

// dense remap index calc: z-fastest [x][y][z], corner order matches CALC_IDX
// ((dx,dy,dz) = 000,001,010,011,100,101,110,111).
#define CALC_IDX_DENSE(L, DD, IDX, F0, F1, F2)                         \
  do {                                                                 \
    const float rs_ = kp.resf[(L)];                                    \
    float xs_ = px * rs_, ys_ = py * rs_, zs_ = pz * rs_;              \
    float bx_ = floorf(xs_), by_ = floorf(ys_), bz_ = floorf(zs_);     \
    (F0) = xs_ - bx_; (F1) = ys_ - by_; (F2) = zs_ - bz_;              \
    uint32 cx_ = (uint32)bx_, cy_ = (uint32)by_, cz_ = (uint32)bz_;    \
    uint32 b_ = (cx_ * (uint32)(DD) + cy_) * (uint32)(DD) + cz_;       \
    (IDX)[0] = b_;                                                     \
    (IDX)[1] = b_ + 1u;                                                \
    (IDX)[2] = b_ + (uint32)(DD);                                      \
    (IDX)[3] = b_ + (uint32)(DD) + 1u;                                 \
    (IDX)[4] = b_ + (uint32)((DD) * (DD));                             \
    (IDX)[5] = b_ + (uint32)((DD) * (DD)) + 1u;                        \
    (IDX)[6] = b_ + (uint32)((DD) * (DD) + (DD));                      \
    (IDX)[7] = b_ + (uint32)((DD) * (DD) + (DD)) + 1u;                 \
  } while (0)

// ---------------- fused encode + MLP ----------------
// 256 threads (4 waves), 256 points per block. MODE 1 = verified r3 artifact;
// MODE 2 = r9 (dense l0/l1, PASSED 281.5us); MODE 3 = pair-packed l0/l1 ONLY
// (4x8B loads instead of 8x4B), l2-l9 hashed.
// HISTORY (do not regress):
//  - r1/r2: feat[40] spills. r3: clean, 289us, PASSED.
//  - r4/r5: occupancy experiments: more TLP is NOT the lever.
//  - r6/r7: load-schedule reorders of the hashed path: FAILED correctness,
//    unexplained. Do NOT reorder the hashed-level loads.
//  - r8 = r3 restore: PASSED 289us. r9 = MODE 2: PASSED 281.5us (+2.6%).
//  - r10 = pairs + dense l2: 285.6us REGRESSION; FETCH 59->200MB = working
//    set (4.7MB) blew the 4MiB per-XCD L2. Dense l2 is BANNED.
//  - NOW MODE 3 = pairs only: working set ~2.4MB < L2; 72 loads/point.
template <int MODE>
__global__ __launch_bounds__(256, 4)
void ngp_fused(const float* __restrict__ x, const float* __restrict__ cr,
               const float* __restrict__ tables, const char* __restrict__ ws8,
               const float* __restrict__ b1, const float* __restrict__ b2,
               const float* __restrict__ b3, float* __restrict__ out,
               int N, KParams kp) {
  __shared__ __align__(16) bf16 Hbuf[256 * 64];
  const int tid = threadIdx.x;
  const int n = blockIdx.x * 256 + tid;
  const int ncl = (n < N) ? n : 0;

  const float px = x[ncl * 3 + 0];
  const float py = x[ncl * 3 + 1];
  const float pz = x[ncl * 3 + 2];
  const float crv = cr[ncl];
  const float* dq = (const float*)(ws8 + DQ_OFF);

  // ---- encode: stream one level-pair (8 bf16 = 16 B) to LDS per group ----
#pragma unroll
  for (int g = 0; g < 5; ++g) {
    bf16x8 v;
#pragma unroll
    for (int h = 0; h < 2; ++h) {
      const int l = g * 2 + h;
      float fx, fy, fz;
      float a0 = 0.f, a1 = 0.f, a2 = 0.f, a3 = 0.f;
      if constexpr (MODE >= 1) {
        unsigned q[8];
        if (MODE == 3 && g == 0) {
          // pair-packed dense: 4 x 8B gathers (corners (z,z+1) per entry).
          const float rs_ = kp.resf[l];
          float xs_ = px * rs_, ys_ = py * rs_, zs_ = pz * rs_;
          float bx_ = floorf(xs_), by_ = floorf(ys_), bz_ = floorf(zs_);
          fx = xs_ - bx_; fy = ys_ - by_; fz = zs_ - bz_;
          uint32 cx_ = (uint32)bx_, cy_ = (uint32)by_, cz_ = (uint32)bz_;
          const uint32 DDc = h ? (uint32)D1 : (uint32)D0;
          uint32 b_ = (cx_ * DDc + cy_) * DDc + cz_;
          const uint2* pt = (const uint2*)(ws8 + (h ? PAIR1_OFF : PAIR0_OFF));
          uint2 P0 = pt[b_];
          uint2 P1 = pt[b_ + DDc];
          uint2 P2 = pt[b_ + DDc * DDc];
          uint2 P3 = pt[b_ + DDc * DDc + DDc];
          q[0] = P0.x; q[1] = P0.y; q[2] = P1.x; q[3] = P1.y;
          q[4] = P2.x; q[5] = P2.y; q[6] = P3.x; q[7] = P3.y;
        } else if (MODE == 2 && g == 0) {
          uint32 idx[8];
          const unsigned* tb;
          if (h == 0) {
            CALC_IDX_DENSE(0, D0, idx, fx, fy, fz);
            tb = (const unsigned*)(ws8 + DENSE0_OFF);
          } else {
            CALC_IDX_DENSE(1, D1, idx, fx, fy, fz);
            tb = (const unsigned*)(ws8 + DENSE1_OFF);
          }
#pragma unroll
          for (int c = 0; c < 8; ++c) q[c] = tb[idx[c]];
        } else {
          uint32 idx[8];
          CALC_IDX(l, idx, fx, fy, fz);
          const unsigned* tb = (const unsigned*)(ws8 + TAB_OFF_B);
#pragma unroll
          for (int c = 0; c < 8; ++c) q[c] = tb[idx[c]];
        }
        float wx1 = fx, wx0 = 1.f - fx, wy1 = fy, wy0 = 1.f - fy, wz1 = fz, wz0 = 1.f - fz;
        float wxy00 = wx0 * wy0, wxy01 = wx0 * wy1, wxy10 = wx1 * wy0, wxy11 = wx1 * wy1;
        float w8[8] = {wxy00 * wz0, wxy00 * wz1, wxy01 * wz0, wxy01 * wz1,
                       wxy10 * wz0, wxy10 * wz1, wxy11 * wz0, wxy11 * wz1};
#pragma unroll
        for (int c = 0; c < 8; ++c) {
          // biased-ubyte unpack -> v_cvt_f32_ubyte{0..3}; the -128*sum(w) term
          // folds to -128 exactly (trilinear weights sum to 1).
          unsigned q_ = q[c];
          a0 = fmaf(w8[c], (float)(q_ & 0xffu), a0);
          a1 = fmaf(w8[c], (float)((q_ >> 8) & 0xffu), a1);
          a2 = fmaf(w8[c], (float)((q_ >> 16) & 0xffu), a2);
          a3 = fmaf(w8[c], (float)(q_ >> 24), a3);
        }
        // l==0: erf(rsqrt(1e-12)) == 1.0f exactly -> skip the transcendental.
        float s = (l == 0) ? dq[0]
                           : erff(rsqrtf(fmaxf(4.0f * (float)l * crv, 1e-12f))) * dq[l];
        v[h * 4 + 0] = (bf16)((a0 - 128.f) * s);
        v[h * 4 + 1] = (bf16)((a1 - 128.f) * s);
        v[h * 4 + 2] = (bf16)((a2 - 128.f) * s);
        v[h * 4 + 3] = (bf16)((a3 - 128.f) * s);
      } else {
        uint32 idx[8];
        CALC_IDX(l, idx, fx, fy, fz);
        const float4* tb4 = (const float4*)tables;  // idx already has l<<16 folded
        float f[8][4];
#pragma unroll
        for (int c = 0; c < 8; ++c) {
          float4 q = tb4[idx[c]];
          f[c][0] = q.x; f[c][1] = q.y; f[c][2] = q.z; f[c][3] = q.w;
        }
        float wx1 = fx, wx0 = 1.f - fx, wy1 = fy, wy0 = 1.f - fy, wz1 = fz, wz0 = 1.f - fz;
        float wxy00 = wx0 * wy0, wxy01 = wx0 * wy1, wxy10 = wx1 * wy0, wxy11 = wx1 * wy1;
        float w8[8] = {wxy00 * wz0, wxy00 * wz1, wxy01 * wz0, wxy01 * wz1,
                       wxy10 * wz0, wxy10 * wz1, wxy11 * wz0, wxy11 * wz1};
#pragma unroll
        for (int c = 0; c < 8; ++c) {
          a0 = fmaf(w8[c], f[c][0], a0);
          a1 = fmaf(w8[c], f[c][1], a1);
          a2 = fmaf(w8[c], f[c][2], a2);
          a3 = fmaf(w8[c], f[c][3], a3);
        }
        float s = (l == 0) ? 1.0f : erff(rsqrtf(fmaxf(4.0f * (float)l * crv, 1e-12f)));
        v[h * 4 + 0] = (bf16)(a0 * s);
        v[h * 4 + 1] = (bf16)(a1 * s);
        v[h * 4 + 2] = (bf16)(a2 * s);
        v[h * 4 + 3] = (bf16)(a3 * s);
      }
    }
    *(bf16x8*)hswz(Hbuf, tid, g * 16) = v;
  }
  {
    bf16x8 z;
#pragma unroll
    for (int j = 0; j < 8; ++j) z[j] = (bf16)0.f;
    *(bf16x8*)hswz(Hbuf, tid, 80) = z;
    *(bf16x8*)hswz(Hbuf, tid, 96) = z;
    *(bf16x8*)hswz(Hbuf, tid, 112) = z;
  }
  __syncthreads();

  const int w = tid >> 6;
  const int lane = tid & 63;
  const int lr = lane & 15;
  const int quad = lane >> 4;
  const bf16* wsb = (const bf16*)ws8;

  gemm_stage(Hbuf, w, lr, quad, wsb + WOFF_W1 + lr * 64 + quad * 8, b1);
  __syncthreads();
  gemm_stage(Hbuf, w, lr, quad, wsb + WOFF_W2 + lr * 64 + quad * 8, b2);
  __syncthreads();

  // ---- stage 3 (64 -> 13) + LDS-staged coalesced output ----
  {
    float b3v = (lr < 13) ? b3[lr] : 0.f;
    f32x4 acc3[4];
#pragma unroll
    for (int ms = 0; ms < 4; ++ms) {
      f32x4 a = {b3v, b3v, b3v, b3v};
      acc3[ms] = a;
    }
    const bf16* B3b = wsb + WOFF_W3 + lr * 64 + quad * 8;
    bf16x8 B3[2];
    B3[0] = *(const bf16x8*)(B3b);
    B3[1] = *(const bf16x8*)(B3b + 32);
#pragma unroll
    for (int ks = 0; ks < 2; ++ks) {
      bf16x8 Af[4];
#pragma unroll
      for (int ms = 0; ms < 4; ++ms)
        Af[ms] = *(const bf16x8*)hswz(Hbuf, w * 64 + ms * 16 + lr, quad * 16 + ks * 64);
#pragma unroll
      for (int ms = 0; ms < 4; ++ms)
        acc3[ms] = __builtin_amdgcn_mfma_f32_16x16x32_bf16(Af[ms], B3[ks], acc3[ms], 0, 0, 0);
    }
    __syncthreads();  // done reading Hbuf; reuse it as f32 output stage
    float* Obuf = (float*)Hbuf;  // 256*13*4 = 13312 B <= 32768 B
#pragma unroll
    for (int ms = 0; ms < 4; ++ms)
#pragma unroll
      for (int r = 0; r < 4; ++r)
        if (lr < 13)
          Obuf[(w * 64 + quad * 4 + ms * 16 + r) * 13 + lr] = acc3[ms][r];
    __syncthreads();

    const int base = blockIdx.x * 256;
    int nrows = N - base;
    if (nrows >= 256) {
      // 13312 B per block, 64B-aligned, fully coalesced float4 stores.
      float4* og4 = (float4*)(out + (size_t)base * 13);
      const float4* Ob4 = (const float4*)Obuf;
#pragma unroll
      for (int i = 0; i < 4; ++i) {
        int j = tid + i * 256;
        if (j < 832) og4[j] = Ob4[j];
      }
    } else {
      const int nfl = nrows * 13;
      float* og = out + (size_t)base * 13;
      for (int j = tid; j < nfl; j += 256) og[j] = Obuf[j];
    }
  }
}

// ---------------- host ----------------
extern "C" void kernel_launch(void* const* d_in, const int* in_sizes, int n_in,
                              void* d_out, int out_size, void* d_ws, size_t ws_size,
                              hipStream_t stream) {
  const float* x      = (const float*)d_in[0];
  const float* cr     = (const float*)d_in[1];
  const float* tables = (const float*)d_in[2];
  const float* W1     = (const float*)d_in[3];
  const float* b1     = (const float*)d_in[4];
  const float* W2     = (const float*)d_in[5];
  const float* b2     = (const float*)d_in[6];
  const float* W3     = (const float*)d_in[7];
  const float* b3     = (const float*)d_in[8];
  float* out = (float*)d_out;
  const int N = in_sizes[1];

  // RES with the exact double arithmetic Python uses (bit-identical hashing).
  KParams kp;
  double B = exp((log(16.0 * pow(2.0, 10.0)) - log(16.0)) / 9.0);
  for (int l = 0; l < LVLS; ++l) kp.resf[l] = (float)floor(16.0 * pow(B, (double)l));

  char* ws8 = (char*)d_ws;
  const int mode = (ws_size >= WS_FULL3) ? 3
                 : (ws_size >= WS_FULL)  ? 2
                 : (ws_size >= WS_NEEDED) ? 1 : 0;

  const int qblocks = (TAB_ELEMS_F / 4 + 255) / 256;  // 2560: covers all builds
  if (mode >= 1) {
    hipMemsetAsync(ws8 + SC_OFF, 0, 64, stream);
    scale_kernel<<<qblocks, 256, 0, stream>>>(tables, (unsigned*)(ws8 + SC_OFF));
    quant_kernel<<<qblocks, 256, 0, stream>>>(W1, W2, W3, tables, ws8, mode);
  } else {
    quant_kernel<<<(W_ELEMS + 255) / 256, 256, 0, stream>>>(W1, W2, W3, tables, ws8, 0);
  }

  int blocks = (N + 255) / 256;
  if (mode == 3)
    ngp_fused<3><<<blocks, 256, 0, stream>>>(x, cr, tables, ws8, b1, b2, b3, out, N, kp);
  else if (mode == 2)
    ngp_fused<2><<<blocks, 256, 0, stream>>>(x, cr, tables, ws8, b1, b2, b3, out, N, kp);
  else if (mode == 1)
    ngp_fused<1><<<blocks, 256, 0, stream>>>(x, cr, tables, ws8, b1, b2, b3, out, N, kp);
  else
    ngp_fused<0><<<blocks, 256, 0, stream>>>(x, cr, tables, ws8, b1, b2, b3, out, N, kp);
}